// Round 12
// baseline (786.304 us; speedup 1.0000x reference)
//
#include <hip/hip_runtime.h>

typedef __attribute__((ext_vector_type(8))) short s16x8;
typedef __attribute__((ext_vector_type(4))) short s16x4;
typedef __attribute__((ext_vector_type(4))) float f32x4;
typedef __attribute__((ext_vector_type(8))) __fp16 f16x8;
typedef __attribute__((ext_vector_type(2))) __fp16 f16x2;

#define AS1 __attribute__((address_space(1)))
#define AS3 __attribute__((address_space(3)))

__device__ __forceinline__ short h16(float f) {
  __fp16 t = (__fp16)f;
  return *(short*)&t;
}
__device__ __forceinline__ float h2f(short s) {
  __fp16 t = *(__fp16*)&s;
  return (float)t;
}
__device__ __forceinline__ unsigned pkh2(float a, float b) {
  f16x2 h = __builtin_amdgcn_cvt_pkrtz(a, b);
  return *(unsigned*)&h;
}
__device__ __forceinline__ float hswish(float v) { return v * fminf(fmaxf(v + 3.f, 0.f), 6.f) * (1.f / 6.f); }
__device__ __forceinline__ int iabs(int v) { return v < 0 ? -v : v; }
__device__ __forceinline__ int gmap(int r) {  // 7x7-strided row -> 14x14 row
  int bb = r / 49, p = r - bb * 49;
  int i = p / 7, j = p - i * 7;
  return bb * 196 + i * 28 + j * 2;
}

#define SC2 0.25503509f  // (1/sqrt(32)) * log2(e)

// ---------------- GEMM: out[M,N] = epi(A[M,K] @ W[N,K]^T), fp16 in, f32 acc ----------------
template <int ACT, int RES, int WF, int WH, int GATHER>
__global__ __launch_bounds__(256) void gemm_k(
    const short* __restrict__ A, const short* __restrict__ W,
    const float* __restrict__ sc, const float* __restrict__ tc,
    const short* __restrict__ Rs, float* __restrict__ oF, short* __restrict__ oH,
    int M, int N, int K, int nwg) {
  __shared__ __align__(16) short As[128 * 64];
  __shared__ __align__(16) short Bs[128 * 64];
  const int tid = threadIdx.x;
  const int lane = tid & 63;
  const int wave = tid >> 6;
  const int wm = wave >> 1, wn = wave & 1;
  const int r15 = lane & 15, kq = lane >> 4;

  const int qc = nwg >> 3, rc = nwg & 7;
  const int xcd = blockIdx.x & 7, off = blockIdx.x >> 3;
  const int wg = (xcd < rc) ? xcd * (qc + 1) + off : rc * (qc + 1) + (xcd - rc) * qc + off;
  const int NTt = N >> 7;
  const int nt = wg % NTt, mt = wg / NTt;
  const int m0 = mt << 7, n0 = nt << 7;

  const int tr = tid >> 3;
  const int col8 = (tid & 7) ^ (tr & 7);
  const short* pa = A + (size_t)(m0 + tr) * K + 8 * col8;
  const short* pb = W + (size_t)(n0 + tr) * K + 8 * col8;
  short* la = As + tid * 8;
  short* lb = Bs + tid * 8;

  f32x4 acc[4][4] = {};
  const int NT = K >> 6;

#define ISSUE(kt)                                                                     \
  {                                                                                   \
    _Pragma("unroll") for (int i = 0; i < 4; ++i) {                                   \
      const short* ga;                                                                \
      if (GATHER)                                                                     \
        ga = A + (size_t)gmap(m0 + tr + 32 * i) * K + 8 * col8 + (kt) * 64;           \
      else                                                                            \
        ga = pa + (size_t)(32 * i) * K + (kt) * 64;                                   \
      __builtin_amdgcn_global_load_lds((const AS1 void*)ga,                           \
                                       (AS3 void*)(la + i * 2048), 16, 0, 0);         \
      __builtin_amdgcn_global_load_lds(                                               \
          (const AS1 void*)(pb + (size_t)(32 * i) * K + (kt) * 64),                   \
          (AS3 void*)(lb + i * 2048), 16, 0, 0);                                      \
    }                                                                                 \
  }

  ISSUE(0)
  for (int kt = 0; kt < NT; ++kt) {
    __syncthreads();  // compiler drains vmcnt(0): DMA for kt landed
    f16x8 af[2][4], bq[2][4];
#pragma unroll
    for (int s = 0; s < 2; ++s) {
      const int cb = s * 64 + kq * 16;
#pragma unroll
      for (int f = 0; f < 4; ++f) {
        int rowA = wm * 64 + f * 16 + r15;
        af[s][f] = *(const f16x8*)((const char*)As + ((rowA * 128 + cb) ^ ((rowA & 7) << 4)));
        int rowB = wn * 64 + f * 16 + r15;
        bq[s][f] = *(const f16x8*)((const char*)Bs + ((rowB * 128 + cb) ^ ((rowB & 7) << 4)));
      }
    }
    __syncthreads();  // all waves done reading LDS
    if (kt + 1 < NT) ISSUE(kt + 1)
    __builtin_amdgcn_sched_barrier(0);
#pragma unroll
    for (int s = 0; s < 2; ++s)
#pragma unroll
      for (int fm = 0; fm < 4; ++fm)
#pragma unroll
        for (int fn = 0; fn < 4; ++fn)
          acc[fm][fn] = __builtin_amdgcn_mfma_f32_16x16x32_f16(af[s][fm], bq[s][fn], acc[fm][fn], 0, 0, 0);
  }
#undef ISSUE

#pragma unroll
  for (int fn = 0; fn < 4; ++fn) {
    const int cn = n0 + wn * 64 + fn * 16 + r15;
    const float scl = sc[cn], tcl = tc[cn];
#pragma unroll
    for (int fm = 0; fm < 4; ++fm) {
#pragma unroll
      for (int j = 0; j < 4; ++j) {
        const int rm = m0 + wm * 64 + fm * 16 + kq * 4 + j;
        float v = acc[fm][fn][j] * scl + tcl;
        if (ACT) v = hswish(v);
        size_t off2 = (size_t)rm * N + cn;
        if (RES) v += h2f(Rs[off2]);
        if (WF) oF[off2] = v;
        if (WH) oH[off2] = h16(v);
      }
    }
  }
}

// ---------------- MFMA attention (layer): S=196, d=32, v=64, H1=4, fp16 ----------------
// round-10 structure (K=32 PV, stride 232) + 2-deep q-tile pipeline:
// QK/softmax of tile i+1 issued before PV of tile i (independent chains overlap).
__global__ __launch_bounds__(256) void attn_mfma_k(const short* __restrict__ QKV,
                                                   const float* __restrict__ BT,
                                                   short* __restrict__ O) {
  __shared__ __align__(16) short Vt[64 * 232];     // fp16 bits, [v][k]
  __shared__ __align__(16) short P[4 * 16 * 232];  // fp16 bits, per wave [q][k]
  const int b = blockIdx.x >> 2, h = blockIdx.x & 3;
  const int tid = threadIdx.x;
  const int lane = tid & 63, wave = tid >> 6;
  const int l15 = lane & 15, g = lane >> 4, g4 = g * 4;
  const short* base = QKV + (size_t)b * (196 * 512);

  // K and Q fragments issued early (overlap with staging)
  f16x8 kf[13];
  {
    const short* kb = base + h * 128 + 32 + 8 * g;
#pragma unroll
    for (int t = 0; t < 13; ++t) {
      int kr = 16 * t + l15;
      if (kr > 195) kr = 195;
      kf[t] = *(const f16x8*)(kb + (size_t)kr * 512);
    }
  }
  f16x8 qf4[4];
#pragma unroll
  for (int i = 0; i < 4; ++i) {
    int qr = 16 * (wave + 4 * i) + l15;
    if (qr > 195) qr = 195;
    qf4[i] = *(const f16x8*)(base + (size_t)qr * 512 + h * 128 + 8 * g);
  }

  // zero pads: Vt cols [196,232), P cols [208,232)
  for (int c = tid; c < 1152; c += 256) {
    int v = c / 18, u = c - v * 18;
    *((unsigned*)Vt + v * 116 + 98 + u) = 0;
  }
  for (int c = tid; c < 768; c += 256) {
    int r = c / 12, u = c - r * 12;
    *((unsigned*)P + r * 116 + 104 + u) = 0;
  }
  // stage V transposed
  for (int c = tid; c < 3136; c += 256) {
    int vp8 = c & 7, rest = c >> 3;
    int vg = rest / 98, kp = rest - vg * 98;
    int vp = vg * 8 + vp8;
    const short* sV = base + (size_t)(2 * kp) * 512 + h * 128 + 64 + 2 * vp;
    unsigned a0 = *(const unsigned*)sV;
    unsigned a1 = *(const unsigned*)(sV + 512);
    *((unsigned*)Vt + (2 * vp) * 116 + kp) = __builtin_amdgcn_perm(a1, a0, 0x05040100u);
    *((unsigned*)Vt + (2 * vp + 1) * 116 + kp) = __builtin_amdgcn_perm(a1, a0, 0x07060302u);
  }
  __syncthreads();

  f32x4 s[13];
#define QK_(ii)                                                                        \
  {                                                                                    \
    __builtin_amdgcn_s_setprio(1);                                                     \
    _Pragma("unroll") for (int t = 0; t < 13; ++t) s[t] =                              \
        __builtin_amdgcn_mfma_f32_16x16x32_f16(kf[t], qf4[ii],                         \
                                               f32x4{0.f, 0.f, 0.f, 0.f}, 0, 0, 0);    \
    __builtin_amdgcn_s_setprio(0);                                                     \
  }
#define SM_(qt_)                                                                       \
  {                                                                                    \
    const float* bt = BT + ((size_t)(h * 208 + 16 * (qt_) + l15)) * 224 + 4 * g;       \
    float m = -1e30f;                                                                  \
    _Pragma("unroll") for (int t = 0; t < 13; ++t) {                                   \
      f32x4 bv = *(const f32x4*)(bt + 16 * t);                                         \
      _Pragma("unroll") for (int j = 0; j < 4; ++j) {                                  \
        float v = fmaf(s[t][j], SC2, bv[j]);                                           \
        s[t][j] = v;                                                                   \
        m = fmaxf(m, v);                                                               \
      }                                                                                \
    }                                                                                  \
    m = fmaxf(m, __shfl_xor(m, 16));                                                   \
    m = fmaxf(m, __shfl_xor(m, 32));                                                   \
    float sum = 0.f;                                                                   \
    _Pragma("unroll") for (int t = 0; t < 13; ++t) {                                   \
      _Pragma("unroll") for (int j = 0; j < 4; ++j) {                                  \
        float p = exp2f(s[t][j] - m);                                                  \
        s[t][j] = p;                                                                   \
        sum += p;                                                                      \
      }                                                                                \
    }                                                                                  \
    sum += __shfl_xor(sum, 16);                                                        \
    sum += __shfl_xor(sum, 32);                                                        \
    float inv = 1.f / sum;                                                             \
    _Pragma("unroll") for (int t = 0; t < 13; ++t) {                                   \
      s[t][0] *= inv; s[t][1] *= inv; s[t][2] *= inv; s[t][3] *= inv;                  \
    }                                                                                  \
  }
#define PW_()                                                                          \
  {                                                                                    \
    unsigned* pw = (unsigned*)P + wave * (16 * 116) + l15 * 116;                       \
    _Pragma("unroll") for (int t = 0; t < 13; ++t) {                                   \
      pw[8 * t + 2 * g] = pkh2(s[t][0], s[t][1]);                                      \
      pw[8 * t + 2 * g + 1] = pkh2(s[t][2], s[t][3]);                                  \
    }                                                                                  \
    asm volatile("s_waitcnt lgkmcnt(0)" ::: "memory");                                 \
    __builtin_amdgcn_sched_barrier(0);                                                 \
  }

  const int nq = wave ? 3 : 4;  // tiles qt = wave+4i < 13
  QK_(0) SM_(wave) PW_()
#pragma unroll
  for (int i = 0; i < 4; ++i) {
    if (i >= nq) break;
    const int qt = wave + 4 * i;
    if (i + 1 < nq) { QK_(i + 1) SM_(wave + 4 * (i + 1)) }  // overlaps PV(i) below
    f32x4 o[4] = {};
    const short* pr = P + (wave * 16 + l15) * 232 + 8 * g;
    const short* vr = Vt + l15 * 232 + 8 * g;
    __builtin_amdgcn_s_setprio(1);
#pragma unroll
    for (int kb = 0; kb < 7; ++kb) {
      f16x8 pa = *(const f16x8*)(pr + 32 * kb);
#pragma unroll
      for (int vt = 0; vt < 4; ++vt) {
        f16x8 vb = *(const f16x8*)(vr + vt * 16 * 232 + 32 * kb);
        o[vt] = __builtin_amdgcn_mfma_f32_16x16x32_f16(pa, vb, o[vt], 0, 0, 0);
      }
    }
    __builtin_amdgcn_s_setprio(0);
#pragma unroll
    for (int vt = 0; vt < 4; ++vt)
#pragma unroll
      for (int j = 0; j < 4; ++j) {
        int qo = 16 * qt + g4 + j;
        if (qo < 196)
          O[(size_t)(b * 196 + qo) * 256 + h * 64 + vt * 16 + l15] = h16(hswish(o[vt][j]));
      }
    if (i + 1 < nq) PW_()  // after PV(i) finished reading P (same-wave DS order)
  }
#undef QK_
#undef SM_
#undef PW_
}

// -------- MFMA subsample attention: q 49(pad 64), k 196, d=32, v=128, H2=8, fp16 --------
// round-10 structure + T14 async-STAGE: half-1 V loads issued to regs before PV half-0.
__global__ __launch_bounds__(256) void subattn_mfma_k(const short* __restrict__ KVg,
                                                      const short* __restrict__ Qg,
                                                      const float* __restrict__ BT,
                                                      short* __restrict__ O2) {
  __shared__ __align__(16) short Vt[64 * 232];     // fp16, one 64-v chunk
  __shared__ __align__(16) short P[4 * 16 * 232];  // fp16
  const int b = blockIdx.x >> 3, h = blockIdx.x & 7;
  const int tid = threadIdx.x;
  const int lane = tid & 63, wave = tid >> 6;
  const int l15 = lane & 15, g = lane >> 4, g4 = g * 4;
  const short* base = KVg + (size_t)b * (196 * 1280) + h * 160;

  // K + Q frags early
  f16x8 kf[13];
#pragma unroll
  for (int t = 0; t < 13; ++t) {
    int kr = 16 * t + l15;
    if (kr > 195) kr = 195;
    kf[t] = *(const f16x8*)(base + (size_t)kr * 1280 + 8 * g);
  }
  const int qr = 16 * wave + l15;
  const int qcl = qr > 48 ? 48 : qr;
  f16x8 qf = *(const f16x8*)(Qg + (size_t)(b * 49 + qcl) * 256 + h * 32 + 8 * g);

  // zero pads (persist across halves)
  for (int c = tid; c < 1152; c += 256) {
    int v = c / 18, u = c - v * 18;
    *((unsigned*)Vt + v * 116 + 98 + u) = 0;
  }
  for (int c = tid; c < 768; c += 256) {
    int r = c / 12, u = c - r * 12;
    *((unsigned*)P + r * 116 + 104 + u) = 0;
  }
  // stage V half 0 directly
  for (int c = tid; c < 3136; c += 256) {
    int vp8 = c & 7, rest = c >> 3;
    int vg = rest / 98, kp = rest - vg * 98;
    int vp = vg * 8 + vp8;
    const short* sp = base + (size_t)(2 * kp) * 1280 + 32 + 2 * vp;
    unsigned a0 = *(const unsigned*)sp;
    unsigned a1 = *(const unsigned*)(sp + 1280);
    *((unsigned*)Vt + (2 * vp) * 116 + kp) = __builtin_amdgcn_perm(a1, a0, 0x05040100u);
    *((unsigned*)Vt + (2 * vp + 1) * 116 + kp) = __builtin_amdgcn_perm(a1, a0, 0x07060302u);
  }
  __syncthreads();

  // QK^T + softmax + P write (single q-tile per wave)
  f32x4 s[13];
  __builtin_amdgcn_s_setprio(1);
#pragma unroll
  for (int t = 0; t < 13; ++t)
    s[t] = __builtin_amdgcn_mfma_f32_16x16x32_f16(kf[t], qf, f32x4{0.f, 0.f, 0.f, 0.f}, 0, 0, 0);
  __builtin_amdgcn_s_setprio(0);
  {
    const float* bt = BT + ((size_t)(h * 64 + qr)) * 224 + 4 * g;
    float m = -1e30f;
#pragma unroll
    for (int t = 0; t < 13; ++t) {
      f32x4 bv = *(const f32x4*)(bt + 16 * t);
#pragma unroll
      for (int j = 0; j < 4; ++j) {
        float v = fmaf(s[t][j], SC2, bv[j]);
        s[t][j] = v;
        m = fmaxf(m, v);
      }
    }
    m = fmaxf(m, __shfl_xor(m, 16));
    m = fmaxf(m, __shfl_xor(m, 32));
    float sum = 0.f;
#pragma unroll
    for (int t = 0; t < 13; ++t)
#pragma unroll
      for (int j = 0; j < 4; ++j) {
        float p = exp2f(s[t][j] - m);
        s[t][j] = p;
        sum += p;
      }
    sum += __shfl_xor(sum, 16);
    sum += __shfl_xor(sum, 32);
    const float inv = 1.f / sum;
    unsigned* pw = (unsigned*)P + wave * (16 * 116) + l15 * 116;
#pragma unroll
    for (int t = 0; t < 13; ++t) {
      pw[8 * t + 2 * g] = pkh2(s[t][0] * inv, s[t][1] * inv);
      pw[8 * t + 2 * g + 1] = pkh2(s[t][2] * inv, s[t][3] * inv);
    }
    asm volatile("s_waitcnt lgkmcnt(0)" ::: "memory");
    __builtin_amdgcn_sched_barrier(0);
  }

  // T14: issue half-1 V loads into registers (latency hides under PV half-0)
  uint2 ra[13];
#pragma unroll
  for (int it = 0; it < 13; ++it) {
    int c = tid + 256 * it;
    int cc = c < 3136 ? c : 3135;
    int vp8 = cc & 7, rest = cc >> 3;
    int vg = rest / 98, kp = rest - vg * 98;
    int vp = vg * 8 + vp8;
    const short* sp = base + (size_t)(2 * kp) * 1280 + 32 + 64 + 2 * vp;
    ra[it].x = *(const unsigned*)sp;
    ra[it].y = *(const unsigned*)(sp + 1280);
  }

  const short* pr = P + (wave * 16 + l15) * 232 + 8 * g;
  const short* vr = Vt + l15 * 232 + 8 * g;
#pragma unroll
  for (int half = 0; half < 2; ++half) {
    if (half) {
      __syncthreads();  // all waves done reading Vt half 0
#pragma unroll
      for (int it = 0; it < 13; ++it) {
        int c = tid + 256 * it;
        if (c >= 3136) break;
        int vp8 = c & 7, rest = c >> 3;
        int vg = rest / 98, kp = rest - vg * 98;
        int vp = vg * 8 + vp8;
        *((unsigned*)Vt + (2 * vp) * 116 + kp) = __builtin_amdgcn_perm(ra[it].y, ra[it].x, 0x05040100u);
        *((unsigned*)Vt + (2 * vp + 1) * 116 + kp) = __builtin_amdgcn_perm(ra[it].y, ra[it].x, 0x07060302u);
      }
      __syncthreads();
    }
    f32x4 o[4] = {};
    __builtin_amdgcn_s_setprio(1);
#pragma unroll
    for (int kb = 0; kb < 7; ++kb) {
      f16x8 pa = *(const f16x8*)(pr + 32 * kb);
#pragma unroll
      for (int vt = 0; vt < 4; ++vt) {
        f16x8 vb = *(const f16x8*)(vr + vt * 16 * 232 + 32 * kb);
        o[vt] = __builtin_amdgcn_mfma_f32_16x16x32_f16(pa, vb, o[vt], 0, 0, 0);
      }
    }
    __builtin_amdgcn_s_setprio(0);
#pragma unroll
    for (int vt = 0; vt < 4; ++vt)
#pragma unroll
      for (int j = 0; j < 4; ++j) {
        int qo = 16 * wave + g4 + j;
        if (qo < 49)
          O2[(size_t)(b * 49 + qo) * 1024 + h * 128 + half * 64 + vt * 16 + l15] =
              h16(hswish(o[vt][j]));
      }
  }
}

// ---------------- utility kernels ----------------
struct Cast9 {
  const float* s[9];
  unsigned off[10];
};
__global__ void cast9_k(Cast9 c, short* __restrict__ WH) {
  int i4 = blockIdx.x * 256 + threadIdx.x;
  int e0 = i4 * 4;
  if (e0 >= 3211264) return;
  int seg = 0;
#pragma unroll
  for (int k = 1; k < 9; ++k) seg += (e0 >= (int)c.off[k]);
  const float4 v = *(const float4*)(c.s[seg] + (e0 - c.off[seg]));
  s16x4 r;
  r[0] = h16(v.x); r[1] = h16(v.y); r[2] = h16(v.z); r[3] = h16(v.w);
  *(s16x4*)(WH + e0) = r;
}

__global__ void cast_h(const float* __restrict__ s, short* __restrict__ d, int n4) {
  int i = blockIdx.x * 256 + threadIdx.x;
  if (i >= n4) return;
  const float4 v = ((const float4*)s)[i];
  s16x4 r;
  r[0] = h16(v.x); r[1] = h16(v.y); r[2] = h16(v.z); r[3] = h16(v.w);
  ((s16x4*)d)[i] = r;
}

// bias table 1: [l][h][208][224] f32 (pre-scaled by log2e); k>=196 -> -30000
__global__ void btab1_k(const float* __restrict__ ab, float* __restrict__ T) {
  int i = blockIdx.x * 256 + threadIdx.x;
  if (i >= 745472) return;
  int k = i % 224;
  int rest = i / 224;
  int q = rest % 208;
  int lh = rest / 208;
  float v = -30000.f;
  if (k < 196) {
    int qc = q < 196 ? q : 195;
    int qi = qc / 14, qj = qc - 14 * qi, ki = k / 14, kj = k - 14 * ki;
    v = ab[lh * 196 + iabs(qi - ki) * 14 + iabs(qj - kj)] * 1.4426950408889634f;
  }
  T[i] = v;
}

// bias table 2: [h][64][224] f32 (pre-scaled by log2e)
__global__ void btab2_k(const float* __restrict__ sb, float* __restrict__ T) {
  int i = blockIdx.x * 256 + threadIdx.x;
  if (i >= 114688) return;
  int k = i % 224;
  int rest = i / 224;
  int q = rest % 64;
  int h = rest / 64;
  float v = -30000.f;
  if (k < 196) {
    int qc = q < 49 ? q : 48;
    int qi = qc / 7, qj = qc - 7 * qi, ki = k / 14, kj = k - 14 * ki;
    v = sb[h * 196 + iabs(2 * qi - ki) * 14 + iabs(2 * qj - kj)] * 1.4426950408889634f;
  }
  T[i] = v;
}

extern "C" void kernel_launch(void* const* d_in, const int* in_sizes, int n_in,
                              void* d_out, int out_size, void* d_ws, size_t ws_size,
                              hipStream_t stream) {
  (void)in_sizes; (void)n_in; (void)out_size; (void)ws_size;
  const float* x = (const float*)d_in[0];
  const float* Wqkv = (const float*)d_in[1];
  const float* qkvs = (const float*)d_in[2];
  const float* qkvt = (const float*)d_in[3];
  const float* Wproj = (const float*)d_in[4];
  const float* projs = (const float*)d_in[5];
  const float* projt = (const float*)d_in[6];
  const float* abias = (const float*)d_in[7];
  const float* W1 = (const float*)d_in[8];
  const float* m1s = (const float*)d_in[9];
  const float* m1t = (const float*)d_in[10];
  const float* W2 = (const float*)d_in[11];
  const float* m2s = (const float*)d_in[12];
  const float* m2t = (const float*)d_in[13];
  const float* Wkv = (const float*)d_in[14];
  const float* kvs = (const float*)d_in[15];
  const float* kvt = (const float*)d_in[16];
  const float* Wq = (const float*)d_in[17];
  const float* qss = (const float*)d_in[18];
  const float* qst = (const float*)d_in[19];
  const float* Wp2 = (const float*)d_in[20];
  const float* p2s = (const float*)d_in[21];
  const float* p2t = (const float*)d_in[22];
  const float* sbias = (const float*)d_in[23];
  const float* Ws1 = (const float*)d_in[24];
  const float* s1s = (const float*)d_in[25];
  const float* s1t = (const float*)d_in[26];
  const float* Ws2 = (const float*)d_in[27];
  const float* s2s = (const float*)d_in[28];
  const float* s2t = (const float*)d_in[29];

  char* ws = (char*)d_ws;
  short* WH = (short*)ws;
  short* WHqkv = WH;                 // 4x512x256
  short* WHproj = WH + 524288;       // 4x256x256
  short* WH1 = WH + 786432;          // 4x512x256
  short* WH2 = WH + 1310720;         // 4x256x512
  short* WHkv = WH + 1835008;        // 1280x256
  short* WHq = WH + 2162688;         // 256x256
  short* WHp2 = WH + 2228224;        // 384x1024
  short* WHs1 = WH + 2621440;        // 768x384
  short* WHs2 = WH + 2916352;        // 384x768

  float* T1 = (float*)(ws + 6422528);     // [4][4][208][224] f32
  float* T2 = (float*)(ws + 9404416);     // [8][64][224] f32
  short* Xh = (short*)(ws + 9863168);     // 50176x256 fp16 residual stream
  short* QKVh = (short*)(ws + 35553280);  // 50176x512 fp16; also Hh
  short* Hh = QKVh;
  short* Oh = (short*)(ws + 86933504);    // 50176x256 fp16
  short* KVh = (short*)(ws + 35553280);   // 50176x1280 fp16 (QKVh/Oh dead)
  short* Qh = (short*)(ws + 170426368);   // 12544x256 fp16
  short* O2h = (short*)(ws + 9863168);    // 12544x1024 fp16 (Xh dead after q GEMM)
  short* X2h = (short*)(ws + 35553280);   // 12544x384 fp16 (KVh dead)
  short* H2h = (short*)(ws + 45187072);   // 12544x768 fp16

  Cast9 c9;
  c9.s[0] = Wqkv; c9.s[1] = Wproj; c9.s[2] = W1; c9.s[3] = W2; c9.s[4] = Wkv;
  c9.s[5] = Wq; c9.s[6] = Wp2; c9.s[7] = Ws1; c9.s[8] = Ws2;
  c9.off[0] = 0; c9.off[1] = 524288; c9.off[2] = 786432; c9.off[3] = 1310720;
  c9.off[4] = 1835008; c9.off[5] = 2162688; c9.off[6] = 2228224;
  c9.off[7] = 2621440; c9.off[8] = 2916352; c9.off[9] = 3211264;
  cast9_k<<<3136, 256, 0, stream>>>(c9, WH);
  btab1_k<<<2912, 256, 0, stream>>>(abias, T1);
  btab2_k<<<448, 256, 0, stream>>>(sbias, T2);
  cast_h<<<12544, 256, 0, stream>>>(x, Xh, 3211264);

  for (int l = 0; l < 4; ++l) {
    gemm_k<0, 0, 0, 1, 0><<<392 * 4, 256, 0, stream>>>(
        Xh, WHqkv + l * 131072, qkvs + l * 512, qkvt + l * 512,
        nullptr, nullptr, QKVh, 50176, 512, 256, 392 * 4);
    attn_mfma_k<<<1024, 256, 0, stream>>>(QKVh, T1 + l * 186368, Oh);
    gemm_k<0, 1, 0, 1, 0><<<392 * 2, 256, 0, stream>>>(
        Oh, WHproj + l * 65536, projs + l * 256, projt + l * 256,
        Xh, nullptr, Xh, 50176, 256, 256, 392 * 2);
    gemm_k<1, 0, 0, 1, 0><<<392 * 4, 256, 0, stream>>>(
        Xh, WH1 + l * 131072, m1s + l * 512, m1t + l * 512,
        nullptr, nullptr, Hh, 50176, 512, 256, 392 * 4);
    gemm_k<0, 1, 0, 1, 0><<<392 * 2, 256, 0, stream>>>(
        Hh, WH2 + l * 131072, m2s + l * 256, m2t + l * 256,
        Xh, nullptr, Xh, 50176, 256, 512, 392 * 2);
  }
  gemm_k<0, 0, 0, 1, 0><<<392 * 10, 256, 0, stream>>>(
      Xh, WHkv, kvs, kvt, nullptr, nullptr, KVh, 50176, 1280, 256, 392 * 10);
  gemm_k<0, 0, 0, 1, 1><<<98 * 2, 256, 0, stream>>>(
      Xh, WHq, qss, qst, nullptr, nullptr, Qh, 12544, 256, 256, 98 * 2);
  subattn_mfma_k<<<2048, 256, 0, stream>>>(KVh, Qh, T2, O2h);
  gemm_k<0, 0, 0, 1, 0><<<98 * 3, 256, 0, stream>>>(
      O2h, WHp2, p2s, p2t, nullptr, nullptr, X2h, 12544, 384, 1024, 98 * 3);
  gemm_k<1, 0, 0, 1, 0><<<98 * 6, 256, 0, stream>>>(
      X2h, WHs1, s1s, s1t, nullptr, nullptr, H2h, 12544, 768, 384, 98 * 6);
  gemm_k<0, 1, 1, 0, 0><<<98 * 3, 256, 0, stream>>>(
      H2h, WHs2, s2s, s2t, X2h, (float*)d_out, nullptr, 12544, 384, 768, 98 * 3);
}

// Round 13
// 744.694 us; speedup vs baseline: 1.0559x; 1.0559x over previous
//
#include <hip/hip_runtime.h>

typedef __attribute__((ext_vector_type(8))) short s16x8;
typedef __attribute__((ext_vector_type(4))) short s16x4;
typedef __attribute__((ext_vector_type(4))) float f32x4;
typedef __attribute__((ext_vector_type(8))) __fp16 f16x8;
typedef __attribute__((ext_vector_type(2))) __fp16 f16x2;

#define AS1 __attribute__((address_space(1)))
#define AS3 __attribute__((address_space(3)))

__device__ __forceinline__ short h16(float f) {
  __fp16 t = (__fp16)f;
  return *(short*)&t;
}
__device__ __forceinline__ float h2f(short s) {
  __fp16 t = *(__fp16*)&s;
  return (float)t;
}
__device__ __forceinline__ unsigned pkh2(float a, float b) {
  f16x2 h = __builtin_amdgcn_cvt_pkrtz(a, b);
  return *(unsigned*)&h;
}
__device__ __forceinline__ float hswish(float v) { return v * fminf(fmaxf(v + 3.f, 0.f), 6.f) * (1.f / 6.f); }
__device__ __forceinline__ int iabs(int v) { return v < 0 ? -v : v; }
__device__ __forceinline__ int gmap(int r) {  // 7x7-strided row -> 14x14 row
  int bb = r / 49, p = r - bb * 49;
  int i = p / 7, j = p - i * 7;
  return bb * 196 + i * 28 + j * 2;
}

// ---------------- GEMM: out[M,N] = epi(A[M,K] @ W[N,K]^T), fp16 in, f32 acc ----------------
template <int ACT, int RES, int WF, int WH, int GATHER>
__global__ __launch_bounds__(256) void gemm_k(
    const short* __restrict__ A, const short* __restrict__ W,
    const float* __restrict__ sc, const float* __restrict__ tc,
    const short* __restrict__ Rs, float* __restrict__ oF, short* __restrict__ oH,
    int M, int N, int K, int nwg) {
  __shared__ __align__(16) short As[128 * 64];
  __shared__ __align__(16) short Bs[128 * 64];
  const int tid = threadIdx.x;
  const int lane = tid & 63;
  const int wave = tid >> 6;
  const int wm = wave >> 1, wn = wave & 1;
  const int r15 = lane & 15, kq = lane >> 4;

  const int qc = nwg >> 3, rc = nwg & 7;
  const int xcd = blockIdx.x & 7, off = blockIdx.x >> 3;
  const int wg = (xcd < rc) ? xcd * (qc + 1) + off : rc * (qc + 1) + (xcd - rc) * qc + off;
  const int NTt = N >> 7;
  const int nt = wg % NTt, mt = wg / NTt;
  const int m0 = mt << 7, n0 = nt << 7;

  const int tr = tid >> 3;
  const int col8 = (tid & 7) ^ (tr & 7);
  const short* pa = A + (size_t)(m0 + tr) * K + 8 * col8;
  const short* pb = W + (size_t)(n0 + tr) * K + 8 * col8;
  short* la = As + tid * 8;
  short* lb = Bs + tid * 8;

  f32x4 acc[4][4] = {};
  const int NT = K >> 6;

#define ISSUE(kt)                                                                     \
  {                                                                                   \
    _Pragma("unroll") for (int i = 0; i < 4; ++i) {                                   \
      const short* ga;                                                                \
      if (GATHER)                                                                     \
        ga = A + (size_t)gmap(m0 + tr + 32 * i) * K + 8 * col8 + (kt) * 64;           \
      else                                                                            \
        ga = pa + (size_t)(32 * i) * K + (kt) * 64;                                   \
      __builtin_amdgcn_global_load_lds((const AS1 void*)ga,                           \
                                       (AS3 void*)(la + i * 2048), 16, 0, 0);         \
      __builtin_amdgcn_global_load_lds(                                               \
          (const AS1 void*)(pb + (size_t)(32 * i) * K + (kt) * 64),                   \
          (AS3 void*)(lb + i * 2048), 16, 0, 0);                                      \
    }                                                                                 \
  }

  ISSUE(0)
  for (int kt = 0; kt < NT; ++kt) {
    __syncthreads();  // compiler drains vmcnt(0): DMA for kt landed
    f16x8 af[2][4], bq[2][4];
#pragma unroll
    for (int s = 0; s < 2; ++s) {
      const int cb = s * 64 + kq * 16;
#pragma unroll
      for (int f = 0; f < 4; ++f) {
        int rowA = wm * 64 + f * 16 + r15;
        af[s][f] = *(const f16x8*)((const char*)As + ((rowA * 128 + cb) ^ ((rowA & 7) << 4)));
        int rowB = wn * 64 + f * 16 + r15;
        bq[s][f] = *(const f16x8*)((const char*)Bs + ((rowB * 128 + cb) ^ ((rowB & 7) << 4)));
      }
    }
    __syncthreads();  // all waves done reading LDS
    if (kt + 1 < NT) ISSUE(kt + 1)
    __builtin_amdgcn_sched_barrier(0);
#pragma unroll
    for (int s = 0; s < 2; ++s)
#pragma unroll
      for (int fm = 0; fm < 4; ++fm)
#pragma unroll
        for (int fn = 0; fn < 4; ++fn)
          acc[fm][fn] = __builtin_amdgcn_mfma_f32_16x16x32_f16(af[s][fm], bq[s][fn], acc[fm][fn], 0, 0, 0);
  }
#undef ISSUE

#pragma unroll
  for (int fn = 0; fn < 4; ++fn) {
    const int cn = n0 + wn * 64 + fn * 16 + r15;
    const float scl = sc[cn], tcl = tc[cn];
#pragma unroll
    for (int fm = 0; fm < 4; ++fm) {
#pragma unroll
      for (int j = 0; j < 4; ++j) {
        const int rm = m0 + wm * 64 + fm * 16 + kq * 4 + j;
        float v = acc[fm][fn][j] * scl + tcl;
        if (ACT) v = hswish(v);
        size_t off2 = (size_t)rm * N + cn;
        if (RES) v += h2f(Rs[off2]);
        if (WF) oF[off2] = v;
        if (WH) oH[off2] = h16(v);
      }
    }
  }
}

// ---------------- MFMA attention (layer): S=196, d=32, v=64, H1=4, fp16 ----------------
// round-10 structure; only change: kf global loads issued BEFORE V-staging so
// their latency hides under the staging phase instead of stalling post-barrier.
__global__ __launch_bounds__(256) void attn_mfma_k(const short* __restrict__ QKV,
                                                   const float* __restrict__ BT,
                                                   short* __restrict__ O) {
  __shared__ __align__(16) short Vt[64 * 232];     // fp16 bits, [v][k], rows padded to 232
  __shared__ __align__(16) short P[4 * 16 * 232];  // fp16 bits, per wave [q][k]
  const int b = blockIdx.x >> 2, h = blockIdx.x & 3;
  const int tid = threadIdx.x;
  const int lane = tid & 63, wave = tid >> 6;
  const int l15 = lane & 15, g = lane >> 4, g4 = g * 4;
  const short* base = QKV + (size_t)b * (196 * 512);

  // K fragments: issue FIRST (latency overlaps staging below)
  f16x8 kf[13];
  {
    const short* kb = base + h * 128 + 32 + 8 * g;
#pragma unroll
    for (int t = 0; t < 13; ++t) {
      int kr = 16 * t + l15;
      if (kr > 195) kr = 195;
      kf[t] = *(const f16x8*)(kb + (size_t)kr * 512);
    }
  }

  // zero pads: Vt cols [196,232), P cols [208,232)
  for (int c = tid; c < 1152; c += 256) {
    int v = c / 18, u = c - v * 18;
    *((unsigned*)Vt + v * 116 + 98 + u) = 0;
  }
  for (int c = tid; c < 768; c += 256) {
    int r = c / 12, u = c - r * 12;
    *((unsigned*)P + r * 116 + 104 + u) = 0;
  }
  // stage V transposed; lane map (vp8 fast over cols) keeps LDS writes ~2-way
  for (int c = tid; c < 3136; c += 256) {
    int vp8 = c & 7, rest = c >> 3;
    int vg = rest / 98, kp = rest - vg * 98;
    int vp = vg * 8 + vp8;
    const short* s = base + (size_t)(2 * kp) * 512 + h * 128 + 64 + 2 * vp;
    unsigned a0 = *(const unsigned*)s;
    unsigned a1 = *(const unsigned*)(s + 512);
    *((unsigned*)Vt + (2 * vp) * 116 + kp) = __builtin_amdgcn_perm(a1, a0, 0x05040100u);
    *((unsigned*)Vt + (2 * vp + 1) * 116 + kp) = __builtin_amdgcn_perm(a1, a0, 0x07060302u);
  }
  __syncthreads();

  for (int qt = wave; qt < 13; qt += 4) {
    int qr = 16 * qt + l15;
    if (qr > 195) qr = 195;
    f16x8 qf = *(const f16x8*)(base + (size_t)qr * 512 + h * 128 + 8 * g);
    f32x4 s[13];
    __builtin_amdgcn_s_setprio(1);
#pragma unroll
    for (int t = 0; t < 13; ++t)
      s[t] = __builtin_amdgcn_mfma_f32_16x16x32_f16(kf[t], qf, f32x4{0.f, 0.f, 0.f, 0.f}, 0, 0, 0);
    __builtin_amdgcn_s_setprio(0);

    const float* bt = BT + ((size_t)(h * 208 + 16 * qt + l15)) * 224 + 4 * g;
    float m = -1e30f;
#pragma unroll
    for (int t = 0; t < 13; ++t) {
      f32x4 bv = *(const f32x4*)(bt + 16 * t);
#pragma unroll
      for (int j = 0; j < 4; ++j) {
        float v = fmaf(s[t][j], 0.17677669529663687f, bv[j]);
        s[t][j] = v;
        m = fmaxf(m, v);
      }
    }
    m = fmaxf(m, __shfl_xor(m, 16));
    m = fmaxf(m, __shfl_xor(m, 32));
    float sum = 0.f;
#pragma unroll
    for (int t = 0; t < 13; ++t)
#pragma unroll
      for (int j = 0; j < 4; ++j) {
        float p = __expf(s[t][j] - m);
        s[t][j] = p;
        sum += p;
      }
    sum += __shfl_xor(sum, 16);
    sum += __shfl_xor(sum, 32);
    const float inv = 1.f / sum;
    unsigned* pw = (unsigned*)P + wave * (16 * 116) + l15 * 116;
#pragma unroll
    for (int t = 0; t < 13; ++t) {
      pw[8 * t + 2 * g] = pkh2(s[t][0] * inv, s[t][1] * inv);
      pw[8 * t + 2 * g + 1] = pkh2(s[t][2] * inv, s[t][3] * inv);
    }
    asm volatile("s_waitcnt lgkmcnt(0)" ::: "memory");
    __builtin_amdgcn_sched_barrier(0);

    f32x4 o[4] = {};
    const short* pr = P + wave * (16 * 232) + l15 * 232 + 8 * g;
    const short* vr = Vt + l15 * 232 + 8 * g;
    __builtin_amdgcn_s_setprio(1);
#pragma unroll
    for (int kb = 0; kb < 7; ++kb) {
      f16x8 pa = *(const f16x8*)(pr + 32 * kb);
#pragma unroll
      for (int vt = 0; vt < 4; ++vt) {
        f16x8 vb = *(const f16x8*)(vr + vt * 16 * 232 + 32 * kb);
        o[vt] = __builtin_amdgcn_mfma_f32_16x16x32_f16(pa, vb, o[vt], 0, 0, 0);
      }
    }
    __builtin_amdgcn_s_setprio(0);
#pragma unroll
    for (int vt = 0; vt < 4; ++vt)
#pragma unroll
      for (int j = 0; j < 4; ++j) {
        int qo = 16 * qt + g4 + j;
        if (qo < 196)
          O[(size_t)(b * 196 + qo) * 256 + h * 64 + vt * 16 + l15] = h16(hswish(o[vt][j]));
      }
  }
}

// -------- MFMA subsample attention: q 49(pad 64), k 196, d=32, v=128, H2=8, fp16 --------
// round-10 structure; only change: qf issued at top alongside kf.
__global__ __launch_bounds__(256) void subattn_mfma_k(const short* __restrict__ KVg,
                                                      const short* __restrict__ Qg,
                                                      const float* __restrict__ BT,
                                                      short* __restrict__ O2) {
  __shared__ __align__(16) short Vt[64 * 232];     // fp16, one 64-v chunk
  __shared__ __align__(16) short P[4 * 16 * 232];  // fp16
  const int b = blockIdx.x >> 3, h = blockIdx.x & 7;
  const int tid = threadIdx.x;
  const int lane = tid & 63, wave = tid >> 6;
  const int l15 = lane & 15, g = lane >> 4, g4 = g * 4;
  const short* base = KVg + (size_t)b * (196 * 1280) + h * 160;

  // K + Q frags first (latency overlaps staging)
  f16x8 kf[13];
#pragma unroll
  for (int t = 0; t < 13; ++t) {
    int kr = 16 * t + l15;
    if (kr > 195) kr = 195;
    kf[t] = *(const f16x8*)(base + (size_t)kr * 1280 + 8 * g);
  }
  const int qr = 16 * wave + l15;
  const int qcl = qr > 48 ? 48 : qr;
  f16x8 qf = *(const f16x8*)(Qg + (size_t)(b * 49 + qcl) * 256 + h * 32 + 8 * g);

  for (int c = tid; c < 1152; c += 256) {
    int v = c / 18, u = c - v * 18;
    *((unsigned*)Vt + v * 116 + 98 + u) = 0;
  }
  for (int c = tid; c < 768; c += 256) {
    int r = c / 12, u = c - r * 12;
    *((unsigned*)P + r * 116 + 104 + u) = 0;
  }

  f32x4 s[13];
  float inv;

  for (int half = 0; half < 2; ++half) {
    if (half) __syncthreads();  // all waves done with prev Vt chunk
    for (int c = tid; c < 3136; c += 256) {
      int vp8 = c & 7, rest = c >> 3;
      int vg = rest / 98, kp = rest - vg * 98;
      int vp = vg * 8 + vp8;
      const short* sp = base + (size_t)(2 * kp) * 1280 + 32 + 64 * half + 2 * vp;
      unsigned a0 = *(const unsigned*)sp;
      unsigned a1 = *(const unsigned*)(sp + 1280);
      *((unsigned*)Vt + (2 * vp) * 116 + kp) = __builtin_amdgcn_perm(a1, a0, 0x05040100u);
      *((unsigned*)Vt + (2 * vp + 1) * 116 + kp) = __builtin_amdgcn_perm(a1, a0, 0x07060302u);
    }
    __syncthreads();

    if (half == 0) {
      __builtin_amdgcn_s_setprio(1);
#pragma unroll
      for (int t = 0; t < 13; ++t)
        s[t] = __builtin_amdgcn_mfma_f32_16x16x32_f16(kf[t], qf, f32x4{0.f, 0.f, 0.f, 0.f}, 0, 0, 0);
      __builtin_amdgcn_s_setprio(0);
      const float* bt = BT + ((size_t)(h * 64 + qr)) * 224 + 4 * g;
      float m = -1e30f;
#pragma unroll
      for (int t = 0; t < 13; ++t) {
        f32x4 bv = *(const f32x4*)(bt + 16 * t);
#pragma unroll
        for (int j = 0; j < 4; ++j) {
          float v = fmaf(s[t][j], 0.17677669529663687f, bv[j]);
          s[t][j] = v;
          m = fmaxf(m, v);
        }
      }
      m = fmaxf(m, __shfl_xor(m, 16));
      m = fmaxf(m, __shfl_xor(m, 32));
      float sum = 0.f;
#pragma unroll
      for (int t = 0; t < 13; ++t)
#pragma unroll
        for (int j = 0; j < 4; ++j) {
          float p = __expf(s[t][j] - m);
          s[t][j] = p;
          sum += p;
        }
      sum += __shfl_xor(sum, 16);
      sum += __shfl_xor(sum, 32);
      inv = 1.f / sum;
      unsigned* pw = (unsigned*)P + wave * (16 * 116) + l15 * 116;
#pragma unroll
      for (int t = 0; t < 13; ++t) {
        pw[8 * t + 2 * g] = pkh2(s[t][0] * inv, s[t][1] * inv);
        pw[8 * t + 2 * g + 1] = pkh2(s[t][2] * inv, s[t][3] * inv);
      }
      asm volatile("s_waitcnt lgkmcnt(0)" ::: "memory");
      __builtin_amdgcn_sched_barrier(0);
    }

    f32x4 o[4] = {};
    const short* pr = P + wave * (16 * 232) + l15 * 232 + 8 * g;
    const short* vr = Vt + l15 * 232 + 8 * g;
    __builtin_amdgcn_s_setprio(1);
#pragma unroll
    for (int kb = 0; kb < 7; ++kb) {
      f16x8 pa = *(const f16x8*)(pr + 32 * kb);
#pragma unroll
      for (int vt = 0; vt < 4; ++vt) {
        f16x8 vb = *(const f16x8*)(vr + vt * 16 * 232 + 32 * kb);
        o[vt] = __builtin_amdgcn_mfma_f32_16x16x32_f16(pa, vb, o[vt], 0, 0, 0);
      }
    }
    __builtin_amdgcn_s_setprio(0);
#pragma unroll
    for (int vt = 0; vt < 4; ++vt)
#pragma unroll
      for (int j = 0; j < 4; ++j) {
        int qo = 16 * wave + g4 + j;
        if (qo < 49)
          O2[(size_t)(b * 49 + qo) * 1024 + h * 128 + half * 64 + vt * 16 + l15] =
              h16(hswish(o[vt][j]));
      }
  }
}

// ---------------- utility kernels ----------------
struct Cast9 {
  const float* s[9];
  unsigned off[10];
};
__global__ void cast9_k(Cast9 c, short* __restrict__ WH) {
  int i4 = blockIdx.x * 256 + threadIdx.x;
  int e0 = i4 * 4;
  if (e0 >= 3211264) return;
  int seg = 0;
#pragma unroll
  for (int k = 1; k < 9; ++k) seg += (e0 >= (int)c.off[k]);
  const float4 v = *(const float4*)(c.s[seg] + (e0 - c.off[seg]));
  s16x4 r;
  r[0] = h16(v.x); r[1] = h16(v.y); r[2] = h16(v.z); r[3] = h16(v.w);
  *(s16x4*)(WH + e0) = r;
}

__global__ void cast_h(const float* __restrict__ s, short* __restrict__ d, int n4) {
  int i = blockIdx.x * 256 + threadIdx.x;
  if (i >= n4) return;
  const float4 v = ((const float4*)s)[i];
  s16x4 r;
  r[0] = h16(v.x); r[1] = h16(v.y); r[2] = h16(v.z); r[3] = h16(v.w);
  ((s16x4*)d)[i] = r;
}

// bias table 1: [l][h][208][224] f32; k>=196 -> -30000
__global__ void btab1_k(const float* __restrict__ ab, float* __restrict__ T) {
  int i = blockIdx.x * 256 + threadIdx.x;
  if (i >= 745472) return;
  int k = i % 224;
  int rest = i / 224;
  int q = rest % 208;
  int lh = rest / 208;
  float v = -30000.f;
  if (k < 196) {
    int qc = q < 196 ? q : 195;
    int qi = qc / 14, qj = qc - 14 * qi, ki = k / 14, kj = k - 14 * ki;
    v = ab[lh * 196 + iabs(qi - ki) * 14 + iabs(qj - kj)];
  }
  T[i] = v;
}

// bias table 2: [h][64][224] f32
__global__ void btab2_k(const float* __restrict__ sb, float* __restrict__ T) {
  int i = blockIdx.x * 256 + threadIdx.x;
  if (i >= 114688) return;
  int k = i % 224;
  int rest = i / 224;
  int q = rest % 64;
  int h = rest / 64;
  float v = -30000.f;
  if (k < 196) {
    int qc = q < 49 ? q : 48;
    int qi = qc / 7, qj = qc - 7 * qi, ki = k / 14, kj = k - 14 * ki;
    v = sb[h * 196 + iabs(2 * qi - ki) * 14 + iabs(2 * qj - kj)];
  }
  T[i] = v;
}

extern "C" void kernel_launch(void* const* d_in, const int* in_sizes, int n_in,
                              void* d_out, int out_size, void* d_ws, size_t ws_size,
                              hipStream_t stream) {
  (void)in_sizes; (void)n_in; (void)out_size; (void)ws_size;
  const float* x = (const float*)d_in[0];
  const float* Wqkv = (const float*)d_in[1];
  const float* qkvs = (const float*)d_in[2];
  const float* qkvt = (const float*)d_in[3];
  const float* Wproj = (const float*)d_in[4];
  const float* projs = (const float*)d_in[5];
  const float* projt = (const float*)d_in[6];
  const float* abias = (const float*)d_in[7];
  const float* W1 = (const float*)d_in[8];
  const float* m1s = (const float*)d_in[9];
  const float* m1t = (const float*)d_in[10];
  const float* W2 = (const float*)d_in[11];
  const float* m2s = (const float*)d_in[12];
  const float* m2t = (const float*)d_in[13];
  const float* Wkv = (const float*)d_in[14];
  const float* kvs = (const float*)d_in[15];
  const float* kvt = (const float*)d_in[16];
  const float* Wq = (const float*)d_in[17];
  const float* qss = (const float*)d_in[18];
  const float* qst = (const float*)d_in[19];
  const float* Wp2 = (const float*)d_in[20];
  const float* p2s = (const float*)d_in[21];
  const float* p2t = (const float*)d_in[22];
  const float* sbias = (const float*)d_in[23];
  const float* Ws1 = (const float*)d_in[24];
  const float* s1s = (const float*)d_in[25];
  const float* s1t = (const float*)d_in[26];
  const float* Ws2 = (const float*)d_in[27];
  const float* s2s = (const float*)d_in[28];
  const float* s2t = (const float*)d_in[29];

  char* ws = (char*)d_ws;
  short* WH = (short*)ws;
  short* WHqkv = WH;                 // 4x512x256
  short* WHproj = WH + 524288;       // 4x256x256
  short* WH1 = WH + 786432;          // 4x512x256
  short* WH2 = WH + 1310720;         // 4x256x512
  short* WHkv = WH + 1835008;        // 1280x256
  short* WHq = WH + 2162688;         // 256x256
  short* WHp2 = WH + 2228224;        // 384x1024
  short* WHs1 = WH + 2621440;        // 768x384
  short* WHs2 = WH + 2916352;        // 384x768

  float* T1 = (float*)(ws + 6422528);     // [4][4][208][224] f32
  float* T2 = (float*)(ws + 9404416);     // [8][64][224] f32
  short* Xh = (short*)(ws + 9863168);     // 50176x256 fp16 residual stream
  short* QKVh = (short*)(ws + 35553280);  // 50176x512 fp16; also Hh
  short* Hh = QKVh;
  short* Oh = (short*)(ws + 86933504);    // 50176x256 fp16
  short* KVh = (short*)(ws + 35553280);   // 50176x1280 fp16 (QKVh/Oh dead)
  short* Qh = (short*)(ws + 170426368);   // 12544x256 fp16
  short* O2h = (short*)(ws + 9863168);    // 12544x1024 fp16 (Xh dead after q GEMM)
  short* X2h = (short*)(ws + 35553280);   // 12544x384 fp16 (KVh dead)
  short* H2h = (short*)(ws + 45187072);   // 12544x768 fp16

  Cast9 c9;
  c9.s[0] = Wqkv; c9.s[1] = Wproj; c9.s[2] = W1; c9.s[3] = W2; c9.s[4] = Wkv;
  c9.s[5] = Wq; c9.s[6] = Wp2; c9.s[7] = Ws1; c9.s[8] = Ws2;
  c9.off[0] = 0; c9.off[1] = 524288; c9.off[2] = 786432; c9.off[3] = 1310720;
  c9.off[4] = 1835008; c9.off[5] = 2162688; c9.off[6] = 2228224;
  c9.off[7] = 2621440; c9.off[8] = 2916352; c9.off[9] = 3211264;
  cast9_k<<<3136, 256, 0, stream>>>(c9, WH);
  btab1_k<<<2912, 256, 0, stream>>>(abias, T1);
  btab2_k<<<448, 256, 0, stream>>>(sbias, T2);
  cast_h<<<12544, 256, 0, stream>>>(x, Xh, 3211264);

  for (int l = 0; l < 4; ++l) {
    gemm_k<0, 0, 0, 1, 0><<<392 * 4, 256, 0, stream>>>(
        Xh, WHqkv + l * 131072, qkvs + l * 512, qkvt + l * 512,
        nullptr, nullptr, QKVh, 50176, 512, 256, 392 * 4);
    attn_mfma_k<<<1024, 256, 0, stream>>>(QKVh, T1 + l * 186368, Oh);
    gemm_k<0, 1, 0, 1, 0><<<392 * 2, 256, 0, stream>>>(
        Oh, WHproj + l * 65536, projs + l * 256, projt + l * 256,
        Xh, nullptr, Xh, 50176, 256, 256, 392 * 2);
    gemm_k<1, 0, 0, 1, 0><<<392 * 4, 256, 0, stream>>>(
        Xh, WH1 + l * 131072, m1s + l * 512, m1t + l * 512,
        nullptr, nullptr, Hh, 50176, 512, 256, 392 * 4);
    gemm_k<0, 1, 0, 1, 0><<<392 * 2, 256, 0, stream>>>(
        Hh, WH2 + l * 131072, m2s + l * 256, m2t + l * 256,
        Xh, nullptr, Xh, 50176, 256, 512, 392 * 2);
  }
  gemm_k<0, 0, 0, 1, 0><<<392 * 10, 256, 0, stream>>>(
      Xh, WHkv, kvs, kvt, nullptr, nullptr, KVh, 50176, 1280, 256, 392 * 10);
  gemm_k<0, 0, 0, 1, 1><<<98 * 2, 256, 0, stream>>>(
      Xh, WHq, qss, qst, nullptr, nullptr, Qh, 12544, 256, 256, 98 * 2);
  subattn_mfma_k<<<2048, 256, 0, stream>>>(KVh, Qh, T2, O2h);
  gemm_k<0, 0, 0, 1, 0><<<98 * 3, 256, 0, stream>>>(
      O2h, WHp2, p2s, p2t, nullptr, nullptr, X2h, 12544, 384, 1024, 98 * 3);
  gemm_k<1, 0, 0, 1, 0><<<98 * 6, 256, 0, stream>>>(
      X2h, WHs1, s1s, s1t, nullptr, nullptr, H2h, 12544, 768, 384, 98 * 6);
  gemm_k<0, 1, 1, 0, 0><<<98 * 3, 256, 0, stream>>>(
      H2h, WHs2, s2s, s2t, X2h, (float*)d_out, nullptr, 12544, 384, 768, 98 * 3);
}